// Round 1
// baseline (4298.831 us; speedup 1.0000x reference)
//
#include <hip/hip_runtime.h>

#define NROWS 131072
#define DIM 128
#define NCB 4
#define CBS 2048
#define BM 64
#define BN 64
#define THREADS 256
#define LDP (DIM + 4) /* 132: stride ≡ 4 (mod 32) banks -> conflict-free-ish b128 reads */

#define ZQ_SIZE ((size_t)NROWS * DIM)
#define CODES_SIZE ((size_t)NROWS * NCB)

__global__ __launch_bounds__(THREADS, 2)
void rvq_kernel(const float* __restrict__ ze,
                const float* __restrict__ cb,
                float* __restrict__ out)
{
    __shared__ __align__(16) float R[BM][LDP];
    __shared__ __align__(16) float C[BN][LDP];
    __shared__ float CN[BN];
    __shared__ float red[4];

    const int tid = threadIdx.x;
    const int tx = tid & 15;
    const int ty = tid >> 4;
    const size_t rows_base = (size_t)blockIdx.x * BM;

    // ---- stage z_e tile into R (residual) ----
    for (int i = tid; i < BM * (DIM / 4); i += THREADS) {
        int row = i >> 5;
        int kw = i & 31;
        float4 v = reinterpret_cast<const float4*>(ze)[rows_base * (DIM / 4) + i];
        *reinterpret_cast<float4*>(&R[row][kw * 4]) = v;
    }
    __syncthreads();

    for (int s = 0; s < NCB; ++s) {
        const float* cbs = cb + (size_t)s * CBS * DIM;

        // ---- x_norm per row (rows ty + 16*rr); each thread sums its 8 dims, tree over tx ----
        float xn[4];
#pragma unroll
        for (int rr = 0; rr < 4; ++rr) {
            const float* rp = &R[ty + 16 * rr][tx * 8];
            float p = 0.0f;
#pragma unroll
            for (int j = 0; j < 8; ++j) p = fmaf(rp[j], rp[j], p);
#pragma unroll
            for (int m = 1; m <= 8; m <<= 1) p += __shfl_xor(p, m);
            xn[rr] = p;
        }

        float bestd[4];
        int besti[4];
#pragma unroll
        for (int rr = 0; rr < 4; ++rr) { bestd[rr] = INFINITY; besti[rr] = 0; }

        for (int chunk = 0; chunk < CBS / BN; ++chunk) {
            __syncthreads(); // previous iteration's C/CN reads (and prev-stage R updates) done

            // stage 64 codes into C
            for (int i = tid; i < BN * (DIM / 4); i += THREADS) {
                int code = i >> 5;
                int kw = i & 31;
                float4 v = reinterpret_cast<const float4*>(cbs)[(size_t)chunk * (BN * (DIM / 4)) + i];
                *reinterpret_cast<float4*>(&C[code][kw * 4]) = v;
            }
            __syncthreads();

            // code norms: 4 lanes per code
            {
                int code = tid >> 2, part = tid & 3;
                const float* cp = &C[code][part * 32];
                float p = 0.0f;
#pragma unroll
                for (int j = 0; j < 32; ++j) p = fmaf(cp[j], cp[j], p);
                p += __shfl_xor(p, 1);
                p += __shfl_xor(p, 2);
                if (part == 0) CN[code] = p;
            }

            // 4x4 register-tile dot products over k
            float acc[4][4];
#pragma unroll
            for (int rr = 0; rr < 4; ++rr)
#pragma unroll
                for (int cc = 0; cc < 4; ++cc) acc[rr][cc] = 0.0f;

#pragma unroll 4
            for (int kk = 0; kk < DIM / 4; ++kk) {
                float4 ra[4], ca[4];
#pragma unroll
                for (int rr = 0; rr < 4; ++rr)
                    ra[rr] = *reinterpret_cast<const float4*>(&R[ty + 16 * rr][kk * 4]);
#pragma unroll
                for (int cc = 0; cc < 4; ++cc)
                    ca[cc] = *reinterpret_cast<const float4*>(&C[tx + 16 * cc][kk * 4]);
#pragma unroll
                for (int rr = 0; rr < 4; ++rr)
#pragma unroll
                    for (int cc = 0; cc < 4; ++cc) {
                        float a = acc[rr][cc];
                        a = fmaf(ra[rr].x, ca[cc].x, a);
                        a = fmaf(ra[rr].y, ca[cc].y, a);
                        a = fmaf(ra[rr].z, ca[cc].z, a);
                        a = fmaf(ra[rr].w, ca[cc].w, a);
                        acc[rr][cc] = a;
                    }
            }
            __syncthreads(); // CN visible; all C reads complete

#pragma unroll
            for (int rr = 0; rr < 4; ++rr)
#pragma unroll
                for (int cc = 0; cc < 4; ++cc) {
                    int code = chunk * BN + tx + 16 * cc;
                    float d = xn[rr] - 2.0f * acc[rr][cc] + CN[tx + 16 * cc];
                    // strict < : codes ascend within this thread -> first-min kept
                    if (d < bestd[rr]) { bestd[rr] = d; besti[rr] = code; }
                }
        }

        // ---- combine (d, idx) across the 16 tx lanes; ties -> lower index ----
#pragma unroll
        for (int rr = 0; rr < 4; ++rr) {
            float d = bestd[rr];
            int bi = besti[rr];
#pragma unroll
            for (int m = 1; m <= 8; m <<= 1) {
                float od = __shfl_xor(d, m);
                int oi = __shfl_xor(bi, m);
                if (od < d || (od == d && oi < bi)) { d = od; bi = oi; }
            }
            bestd[rr] = d;
            besti[rr] = bi;
        }

        // ---- write codes (as float values) ----
        if (tx == 0) {
#pragma unroll
            for (int rr = 0; rr < 4; ++rr) {
                size_t grow = rows_base + (size_t)(ty + 16 * rr);
                out[ZQ_SIZE + grow * NCB + s] = (float)besti[rr];
            }
        }

        // ---- residual -= chosen code; each thread updates its 8 dims of its 4 rows ----
#pragma unroll
        for (int rr = 0; rr < 4; ++rr) {
            int row = ty + 16 * rr;
            const float* q = cbs + (size_t)besti[rr] * DIM + tx * 8;
            float* rp = &R[row][tx * 8];
            float4 q0 = *reinterpret_cast<const float4*>(q);
            float4 q1 = *reinterpret_cast<const float4*>(q + 4);
            float4 r0 = *reinterpret_cast<float4*>(rp);
            float4 r1 = *reinterpret_cast<float4*>(rp + 4);
            r0.x -= q0.x; r0.y -= q0.y; r0.z -= q0.z; r0.w -= q0.w;
            r1.x -= q1.x; r1.y -= q1.y; r1.z -= q1.z; r1.w -= q1.w;
            *reinterpret_cast<float4*>(rp) = r0;
            *reinterpret_cast<float4*>(rp + 4) = r1;
        }
        // no barrier needed here: next-stage xn reads only this thread's own dims;
        // the chunk-loop-top barrier guards cross-thread R reads in the k-loop.
    }

    __syncthreads(); // final residual fully written before cross-thread reads

    // ---- z_q = z_e - r_final, and loss partial sum(r^2) ----
    float lsum = 0.0f;
    for (int i = tid; i < BM * (DIM / 4); i += THREADS) {
        int row = i >> 5;
        int kw = i & 31;
        float4 z = reinterpret_cast<const float4*>(ze)[rows_base * (DIM / 4) + i];
        float4 r = *reinterpret_cast<float4*>(&R[row][kw * 4]);
        float4 o;
        o.x = z.x - r.x; o.y = z.y - r.y; o.z = z.z - r.z; o.w = z.w - r.w;
        reinterpret_cast<float4*>(out)[rows_base * (DIM / 4) + i] = o;
        lsum = fmaf(r.x, r.x, lsum);
        lsum = fmaf(r.y, r.y, lsum);
        lsum = fmaf(r.z, r.z, lsum);
        lsum = fmaf(r.w, r.w, lsum);
    }
    // block-reduce lsum
#pragma unroll
    for (int m = 1; m < 64; m <<= 1) lsum += __shfl_xor(lsum, m);
    if ((tid & 63) == 0) red[tid >> 6] = lsum;
    __syncthreads();
    if (tid == 0) {
        float t = red[0] + red[1] + red[2] + red[3];
        atomicAdd(out + ZQ_SIZE + CODES_SIZE,
                  t * (1.25f / ((float)NROWS * (float)DIM)));
    }
}

extern "C" void kernel_launch(void* const* d_in, const int* in_sizes, int n_in,
                              void* d_out, int out_size, void* d_ws, size_t ws_size,
                              hipStream_t stream)
{
    const float* ze = (const float*)d_in[0];
    const float* cb = (const float*)d_in[1];
    float* out = (float*)d_out;

    // loss slot accumulated via atomics -> zero it first (async, capture-safe)
    hipMemsetAsync(out + ZQ_SIZE + CODES_SIZE, 0, sizeof(float), stream);

    dim3 grid(NROWS / BM);
    rvq_kernel<<<grid, THREADS, 0, stream>>>(ze, cb, out);
}

// Round 3
// 857.649 us; speedup vs baseline: 5.0123x; 5.0123x over previous
//
#include <hip/hip_runtime.h>

typedef float v16f __attribute__((ext_vector_type(16)));
typedef _Float16 v8h __attribute__((ext_vector_type(8)));

#define NROWS 131072
#define DIM 128
#define NCB 4
#define CBS 2048
#define ZQ_SIZE ((size_t)NROWS * DIM)
#define CODES_SIZE ((size_t)NROWS * NCB)
#define CHUNK_BYTES 16384
#define CBQ_TOTAL ((size_t)NCB * 64 * CHUNK_BYTES)  /* 4 MiB */
#define INV4096 2.44140625e-4f

#define MFMA16(a, b, c) __builtin_amdgcn_mfma_f32_32x32x16_f16((a), (b), (c), 0, 0, 0)

// Tile codebook into per-chunk f16 2-limb image.
// chunk block (16384 B) layout: frag(L,c) at (L*8+c)*1024 + lane*16,
// holding limb L of cb[s][32q+col][16c + 8h + j], lane = h*32+col, j=0..7.
__global__ void prep_cb(const float* __restrict__ cb, _Float16* __restrict__ cbq) {
    const int g = blockIdx.x * 256 + threadIdx.x;   // 65536 threads
    const int c   = g & 7;
    const int col = (g >> 3) & 31;
    const int q   = (g >> 8) & 63;
    const int s   = g >> 14;
    const float* src = cb + (size_t)(s * CBS + q * 32 + col) * DIM + 16 * c;
    _Float16* base = cbq + (size_t)(s * 64 + q) * 8192;  // f16 elems
#pragma unroll
    for (int hh = 0; hh < 2; ++hh) {
        v8h p0, p1;
#pragma unroll
        for (int j = 0; j < 8; ++j) {
            const float v = src[8 * hh + j];
            const _Float16 h0 = (_Float16)v;
            const float t = v - (float)h0;        // exact
            p0[j] = h0;
            p1[j] = (_Float16)(t * 4096.0f);      // scaled limb: normal range
        }
        *reinterpret_cast<v8h*>(base + (size_t)c * 512 + (hh * 32 + col) * 8) = p0;
        *reinterpret_cast<v8h*>(base + (size_t)(8 + c) * 512 + (hh * 32 + col) * 8) = p1;
    }
}

__global__ void prep_cn(const float* __restrict__ cb, float* __restrict__ cn) {
    const int g = blockIdx.x * 256 + threadIdx.x;   // 8192 threads
    const float* src = cb + (size_t)g * DIM;
    float acc = 0.0f;
    for (int i = 0; i < 32; ++i) {
        const float4 v = *reinterpret_cast<const float4*>(src + 4 * i);
        acc = fmaf(v.x, v.x, acc); acc = fmaf(v.y, v.y, acc);
        acc = fmaf(v.z, v.z, acc); acc = fmaf(v.w, v.w, acc);
    }
    cn[g] = acc;
}

__global__ __launch_bounds__(256, 2)
void rvq_main(const float* __restrict__ ze, const float* __restrict__ cbf,
              const _Float16* __restrict__ cbq, const float* __restrict__ cn,
              float* __restrict__ out)
{
    __shared__ __align__(16) char BB[2][CHUNK_BYTES];
    __shared__ float XN[4][32];
    __shared__ int   BIs[4][32];

    const int tid  = threadIdx.x;
    const int wid  = tid >> 6;
    const int lane = tid & 63;
    const int col  = lane & 31;
    const int h    = lane >> 5;
    const int rowbase = blockIdx.x * 128 + wid * 32;
    const int myrow   = rowbase + col;

    // residual in registers: res[c][j] = r[myrow][16c + 8h + j]
    float res[8][8];
#pragma unroll
    for (int c = 0; c < 8; ++c) {
#pragma unroll
        for (int w2 = 0; w2 < 2; ++w2) {
            const float4 v = *reinterpret_cast<const float4*>(
                ze + (size_t)myrow * DIM + 16 * c + 8 * h + 4 * w2);
            res[c][4 * w2 + 0] = v.x; res[c][4 * w2 + 1] = v.y;
            res[c][4 * w2 + 2] = v.z; res[c][4 * w2 + 3] = v.w;
        }
    }

    for (int s = 0; s < NCB; ++s) {
        // ---- quantize residual to f16 2-limb fragments; x_norm ----
        v8h A0[8], A1[8];
        float pc[8];
#pragma unroll
        for (int c = 0; c < 8; ++c) {
            float p[8];
#pragma unroll
            for (int j = 0; j < 8; ++j) {
                const float v = res[c][j];
                p[j] = v * v;
                const _Float16 h0 = (_Float16)v;
                const float t = v - (float)h0;    // exact
                A0[c][j] = h0;
                A1[c][j] = (_Float16)(t * 4096.0f);
            }
            pc[c] = ((p[0] + p[1]) + (p[2] + p[3])) + ((p[4] + p[5]) + (p[6] + p[7]));
        }
        float xnp = ((pc[0] + pc[1]) + (pc[2] + pc[3])) + ((pc[4] + pc[5]) + (pc[6] + pc[7]));
        const float xn_own = xnp + __shfl_xor(xnp, 32);
        if (h == 0) XN[wid][col] = xn_own;
        __syncthreads();
        float xns[16];
#pragma unroll
        for (int r = 0; r < 16; ++r) xns[r] = XN[wid][(r & 3) + 8 * (r >> 2) + 4 * h];

        // ---- stage chunk 0 ----
        {
            const char* g0 = (const char*)cbq + (size_t)(s * 64) * CHUNK_BYTES;
#pragma unroll
            for (int i = 0; i < 4; ++i) {
                const int blk = i * 4 + wid;
                __builtin_amdgcn_global_load_lds(
                    (const __attribute__((address_space(1))) void*)(g0 + blk * 1024 + lane * 16),
                    (__attribute__((address_space(3))) void*)(&BB[0][blk * 1024]),
                    16, 0, 0);
            }
        }
        __syncthreads();

        float bestd[16]; int besti[16];
#pragma unroll
        for (int r = 0; r < 16; ++r) { bestd[r] = INFINITY; besti[r] = 0; }

#pragma unroll 1
        for (int q = 0; q < 64; ++q) {
            const int cur = q & 1;
            if (q < 63) {  // prefetch next chunk into other buffer
                const char* gq = (const char*)cbq + (size_t)(s * 64 + q + 1) * CHUNK_BYTES;
#pragma unroll
                for (int i = 0; i < 4; ++i) {
                    const int blk = i * 4 + wid;
                    __builtin_amdgcn_global_load_lds(
                        (const __attribute__((address_space(1))) void*)(gq + blk * 1024 + lane * 16),
                        (__attribute__((address_space(3))) void*)(&BB[cur ^ 1][blk * 1024]),
                        16, 0, 0);
                }
            }
            const float cnv = cn[s * CBS + q * 32 + col];
            const char* bb = &BB[cur][0];
            v16f aM, aC;
            {
                const v8h b0 = *reinterpret_cast<const v8h*>(bb + lane * 16);
                const v8h b1 = *reinterpret_cast<const v8h*>(bb + 8 * 1024 + lane * 16);
                const v16f Z = {0.f,0.f,0.f,0.f,0.f,0.f,0.f,0.f,0.f,0.f,0.f,0.f,0.f,0.f,0.f,0.f};
                aM = MFMA16(A0[0], b0, Z);
                aC = MFMA16(A1[0], b0, Z);
                aC = MFMA16(A0[0], b1, aC);
            }
#pragma unroll
            for (int c = 1; c < 8; ++c) {
                const v8h b0 = *reinterpret_cast<const v8h*>(bb + (size_t)c * 1024 + lane * 16);
                const v8h b1 = *reinterpret_cast<const v8h*>(bb + (size_t)(8 + c) * 1024 + lane * 16);
                aM = MFMA16(A0[c], b0, aM);
                aC = MFMA16(A1[c], b0, aC);
                aC = MFMA16(A0[c], b1, aC);
            }
            const int code = q * 32 + col;
#pragma unroll
            for (int r = 0; r < 16; ++r) {
                const float dotf = fmaf(aC[r], INV4096, aM[r]);
                const float d = fmaf(-2.0f, dotf, xns[r]) + cnv;  // matches ref rounding
                if (d < bestd[r]) { bestd[r] = d; besti[r] = code; }
            }
            __syncthreads();
        }

        // ---- argmin across 32 cols (within each half-wave); ties -> lower idx ----
#pragma unroll
        for (int r = 0; r < 16; ++r) {
            float d = bestd[r]; int bi = besti[r];
#pragma unroll
            for (int m = 1; m <= 16; m <<= 1) {
                const float od = __shfl_xor(d, m);
                const int   oi = __shfl_xor(bi, m);
                const bool take = (od < d) || ((od == d) && (oi < bi));
                d  = take ? od : d;
                bi = take ? oi : bi;
            }
            bestd[r] = d; besti[r] = bi;
        }

        if (col == 0) {
#pragma unroll
            for (int r = 0; r < 16; ++r) {
                const int row16 = (r & 3) + 8 * (r >> 2) + 4 * h;
                BIs[wid][row16] = besti[r];
                out[ZQ_SIZE + (size_t)(rowbase + row16) * NCB + s] = (float)besti[r];
            }
        }
        __syncthreads();

        // ---- residual -= chosen code (exact f32, original codebook) ----
        const int mybest = BIs[wid][col];
        const float* qrow = cbf + ((size_t)(s * CBS) + mybest) * DIM + 8 * h;
#pragma unroll
        for (int c = 0; c < 8; ++c) {
#pragma unroll
            for (int w2 = 0; w2 < 2; ++w2) {
                const float4 v = *reinterpret_cast<const float4*>(qrow + 16 * c + 4 * w2);
                res[c][4 * w2 + 0] -= v.x; res[c][4 * w2 + 1] -= v.y;
                res[c][4 * w2 + 2] -= v.z; res[c][4 * w2 + 3] -= v.w;
            }
        }
    }

    // ---- epilogue: z_q = z_e - r_final, loss = 1.25*mean(r^2) ----
    float lsum = 0.0f;
#pragma unroll
    for (int c = 0; c < 8; ++c) {
#pragma unroll
        for (int w2 = 0; w2 < 2; ++w2) {
            const float4 z = *reinterpret_cast<const float4*>(
                ze + (size_t)myrow * DIM + 16 * c + 8 * h + 4 * w2);
            const float r0 = res[c][4 * w2 + 0], r1 = res[c][4 * w2 + 1];
            const float r2 = res[c][4 * w2 + 2], r3 = res[c][4 * w2 + 3];
            float4 o;
            o.x = z.x - r0; o.y = z.y - r1; o.z = z.z - r2; o.w = z.w - r3;
            *reinterpret_cast<float4*>(out + (size_t)myrow * DIM + 16 * c + 8 * h + 4 * w2) = o;
            lsum = fmaf(r0, r0, lsum); lsum = fmaf(r1, r1, lsum);
            lsum = fmaf(r2, r2, lsum); lsum = fmaf(r3, r3, lsum);
        }
    }
#pragma unroll
    for (int m = 1; m < 64; m <<= 1) lsum += __shfl_xor(lsum, m);
    if (lane == 0)
        atomicAdd(out + ZQ_SIZE + CODES_SIZE, lsum * (1.25f / 16777216.0f));
}

extern "C" void kernel_launch(void* const* d_in, const int* in_sizes, int n_in,
                              void* d_out, int out_size, void* d_ws, size_t ws_size,
                              hipStream_t stream)
{
    const float* ze  = (const float*)d_in[0];
    const float* cbf = (const float*)d_in[1];
    float* out = (float*)d_out;

    _Float16* cbq = (_Float16*)d_ws;
    float* cnall = (float*)((char*)d_ws + CBQ_TOTAL);

    hipMemsetAsync(out + ZQ_SIZE + CODES_SIZE, 0, sizeof(float), stream);

    prep_cb<<<256, 256, 0, stream>>>(cbf, cbq);
    prep_cn<<<32, 256, 0, stream>>>(cbf, cnall);
    rvq_main<<<NROWS / 128, 256, 0, stream>>>(ze, cbf, cbq, cnall, out);
}